// Round 3
// baseline (140.015 us; speedup 1.0000x reference)
//
#include <hip/hip_runtime.h>

// CombinePatches fold, round 3: full-line-per-lane gather.
// Lane q owns patch zw=q's 64B slot (i,j,l=0..3) per (i,j) combo:
//   l=0,1 -> partial for output w-pair q   (accA)
//   l=2,3 -> partial for output w-pair q+1 (accB)
// After the (i,j) loop, pair q = accA(q) + shfl_up(accB, 1). Every 64B patch
// line is read exactly once by exactly one lane -> nontemporal loads bypass
// L2 (zero reuse). One 8-dword shuffle per thread replaces per-combo
// half-line sharing through the cache.
// Counts are separable, cnt = ci*cj*cl in {1,2,4,8} -> exact reciprocal.

constexpr int OD = 31, OH = 63, OW = 63;
// patches: [2,31,63,63,256] f32 (64 float4 per patch, slot = i*16+j*4+l)
// out:     [2,64,128,128,4]  f32

using f4 = __attribute__((ext_vector_type(4))) float;

__global__ __launch_bounds__(256) void fold_line_kernel(
    const f4* __restrict__ p, f4* __restrict__ out)
{
    int t = blockIdx.x * 256 + threadIdx.x;   // 2^20 threads
    int q = t & 63;                           // lane ; patch zw=q ; out w=2q,2q+1
    int h = (t >> 6) & 127;
    int d = (t >> 13) & 63;
    int b = t >> 19;

    const int i0 = d & 1, j0 = h & 1;
    const int zdA = (d - i0) >> 1;
    const int zhA = (h - j0) >> 1;

    const int ci = (zdA <= OD - 1) + (zdA >= 1);
    const int cj = (zhA <= OH - 1) + (zhA >= 1);
    const int cl = (q <= OW - 1) + (q >= 1);
    const float inv = 1.0f / (float)(ci * cj * cl);

    f4 aAe = (f4)0.0f, aAo = (f4)0.0f;   // l=0,1 -> this pair
    f4 aBe = (f4)0.0f, aBo = (f4)0.0f;   // l=2,3 -> next pair

    const bool qok = (q <= OW - 1);       // patch zw=q exists (q<=62)

    #pragma unroll
    for (int ii = 0; ii < 2; ++ii) {
        const int zd = zdA - ii;
        if ((unsigned)zd > (unsigned)(OD - 1)) continue;   // wave-uniform
        const int i = i0 + 2 * ii;
        #pragma unroll
        for (int jj = 0; jj < 2; ++jj) {
            const int zh = zhA - jj;
            if ((unsigned)zh > (unsigned)(OH - 1)) continue;  // wave-uniform
            const int j = j0 + 2 * jj;
            if (qok) {
                const f4* s = p + ((((b * OD + zd) * OH + zh) * OW + q) << 6)
                                + (i << 4) + (j << 2);
                f4 v0 = __builtin_nontemporal_load(s + 0);   // l=0
                f4 v1 = __builtin_nontemporal_load(s + 1);   // l=1
                f4 v2 = __builtin_nontemporal_load(s + 2);   // l=2
                f4 v3 = __builtin_nontemporal_load(s + 3);   // l=3
                aAe += v0; aAo += v1;
                aBe += v2; aBo += v3;
            }
        }
    }

    // pair q gets accB from lane q-1 (l=2,3 of patch q-1)
    f4 sBe, sBo;
    #pragma unroll
    for (int k = 0; k < 4; ++k) {
        sBe[k] = __shfl_up(aBe[k], 1, 64);
        sBo[k] = __shfl_up(aBo[k], 1, 64);
    }
    if (q == 0) { sBe = (f4)0.0f; sBo = (f4)0.0f; }

    f4 oe = (aAe + sBe) * inv;
    f4 oo = (aAo + sBo) * inv;

    const int n = ((t >> 6) << 7) + (q << 1);
    __builtin_nontemporal_store(oe, &out[n]);
    __builtin_nontemporal_store(oo, &out[n + 1]);
}

extern "C" void kernel_launch(void* const* d_in, const int* in_sizes, int n_in,
                              void* d_out, int out_size, void* d_ws, size_t ws_size,
                              hipStream_t stream)
{
    const f4* patches = (const f4*)d_in[0];   // [2,31,63,63,256] f32
    f4* out = (f4*)d_out;                     // [2,64,128,128,4] f32

    const int total = 2 * 64 * 128 * 64;      // 2^20 threads (one per w-pair)
    fold_line_kernel<<<total / 256, 256, 0, stream>>>(patches, out);
}

// Round 4
// 64.572 us; speedup vs baseline: 2.1684x; 2.1684x over previous
//
#include <hip/hip_runtime.h>

// CombinePatches fold, round 4: gather (round-2 structure, plain cached loads)
// + 4-way ILP. Each thread computes 4 voxel-PAIRS at h, h+32, h+64, h+96 for
// one (b,d,w-pair). 4 independent load streams -> ~4x in-flight bytes per
// wave to cover memory latency. All zd/zh bounds branches remain wave-uniform
// (lanes span only q). Counts separable: cnt = ci*cj*cl in {1,2,4,8}.

constexpr int OD = 31, OH = 63, OW = 63;
// patches: [2,31,63,63,256] f32 = 64 float4/patch, slot f4 = i*16 + j*4 + l
// out:     [2,64,128,128,4]  f32 = 1 float4/voxel

using f4 = __attribute__((ext_vector_type(4))) float;

__global__ __launch_bounds__(256) void fold_ilp4_kernel(
    const f4* __restrict__ p, f4* __restrict__ out)
{
    int t = blockIdx.x * 256 + threadIdx.x;   // 2^18 threads
    int q  = t & 63;                          // w = 2q, 2q+1
    int h0 = (t >> 6) & 31;                   // streams: h = h0 + 32*s
    int d  = (t >> 11) & 63;
    int b  = t >> 17;

    const int i0  = d & 1;
    const int zdA = (d - i0) >> 1;            // zd candidates: zdA, zdA-1
    const int j0c = h0 & 1;                   // same parity for all 4 streams
    const int zh0 = (h0 - j0c) >> 1;          // zhA_s = zh0 + 16*s

    const int  ci  = (zdA <= OD - 1) + (zdA >= 1);
    const bool qhi = (q <= OW - 1);
    const bool qlo = (q >= 1);
    const int  cl  = (int)qhi + (int)qlo;

    f4 ae[4], ao[4];
    #pragma unroll
    for (int s = 0; s < 4; ++s) { ae[s] = (f4)0.0f; ao[s] = (f4)0.0f; }

    #pragma unroll
    for (int ii = 0; ii < 2; ++ii) {
        const int zd = zdA - ii;
        if ((unsigned)zd > (unsigned)(OD - 1)) continue;    // wave-uniform
        const int i = i0 + 2 * ii;
        #pragma unroll
        for (int jj = 0; jj < 2; ++jj) {
            const int j    = j0c + 2 * jj;
            const int koff = (i << 4) + (j << 2);
            #pragma unroll
            for (int s = 0; s < 4; ++s) {
                const int zh = zh0 + 16 * s - jj;
                if ((unsigned)zh > (unsigned)(OH - 1)) continue;  // uniform
                const int rowbase = (((b * OD + zd) * OH + zh) * OW) << 6;
                if (qhi) {
                    const f4* sp = p + rowbase + (q << 6) + koff;       // l=0,1
                    ae[s] += sp[0];
                    ao[s] += sp[1];
                }
                if (qlo) {
                    const f4* sp = p + rowbase + ((q - 1) << 6) + koff + 2; // l=2,3
                    ae[s] += sp[0];
                    ao[s] += sp[1];
                }
            }
        }
    }

    #pragma unroll
    for (int s = 0; s < 4; ++s) {
        const int h   = h0 + 32 * s;
        const int zhA = zh0 + 16 * s;
        const int cj  = (zhA <= OH - 1) + (zhA >= 1);
        const float inv = 1.0f / (float)(ci * cj * cl);   // {1..8}: exact
        // out f4 index: ((b*64 + d)*128 + h)*128 + 2q
        const int n = ((((b << 6) + d) << 7) + h) * 128 + (q << 1);
        out[n]     = ae[s] * inv;
        out[n + 1] = ao[s] * inv;
    }
}

extern "C" void kernel_launch(void* const* d_in, const int* in_sizes, int n_in,
                              void* d_out, int out_size, void* d_ws, size_t ws_size,
                              hipStream_t stream)
{
    const f4* patches = (const f4*)d_in[0];   // [2,31,63,63,256] f32
    f4* out = (f4*)d_out;                     // [2,64,128,128,4] f32

    const int total = 2 * 64 * 32 * 64;       // 2^18 threads (4 pairs each)
    fold_ilp4_kernel<<<total / 256, 256, 0, stream>>>(patches, out);
}

// Round 5
// 53.601 us; speedup vs baseline: 2.6122x; 1.2047x over previous
//
#include <hip/hip_runtime.h>

// CombinePatches fold, round 5: round-2 per-thread gather body, re-packaged so
// each 1024-thread block covers a 4x4 (d,h) quad x full w. The block then
// consumes its center (zd,zh) patch row fully densely (all 16 (i,j) slices of
// a contiguous 64KB region) and half of each neighbor row -> ~2x denser
// DRAM/L3 footprint per block, identical per-wave coalescing (wave = one
// (d,h), lanes span w-pairs q). Counts separable: cnt = ci*cj*cl in {1,2,4,8}.

constexpr int OD = 31, OH = 63, OW = 63;
// patches: [2,31,63,63,256] f32 = 64 float4/patch, slot f4 = i*16 + j*4 + l
// out:     [2,64,128,128,4]  f32

using f4 = __attribute__((ext_vector_type(4))) float;

__global__ __launch_bounds__(1024) void fold_quad_kernel(
    const f4* __restrict__ p, f4* __restrict__ out)
{
    // block: b (1b) | dq (4b, d-quad) | hq (5b, h-quad)
    const int hq = blockIdx.x & 31;
    const int dq = (blockIdx.x >> 5) & 15;
    const int b  = blockIdx.x >> 9;
    // thread: wave = (dl, hl) in 4x4 quad; lanes = q (w-pair)
    const int q  = threadIdx.x & 63;
    const int hl = (threadIdx.x >> 6) & 3;
    const int dl = threadIdx.x >> 8;

    const int d = (dq << 2) + dl;
    const int h = (hq << 2) + hl;

    const int i0 = d & 1, j0 = h & 1;
    const int zdA = (d - i0) >> 1;
    const int zhA = (h - j0) >> 1;

    const int ci = (zdA <= OD - 1) + (zdA >= 1);
    const int cj = (zhA <= OH - 1) + (zhA >= 1);
    const bool qhi = (q <= OW - 1);
    const bool qlo = (q >= 1);
    const int cl = (int)qhi + (int)qlo;
    const float inv = 1.0f / (float)(ci * cj * cl);   // {1..8}: exact

    f4 ae = (f4)0.0f, ao = (f4)0.0f;

    #pragma unroll
    for (int ii = 0; ii < 2; ++ii) {
        const int zd = zdA - ii;
        if ((unsigned)zd > (unsigned)(OD - 1)) continue;   // wave-uniform
        const int i = i0 + 2 * ii;
        #pragma unroll
        for (int jj = 0; jj < 2; ++jj) {
            const int zh = zhA - jj;
            if ((unsigned)zh > (unsigned)(OH - 1)) continue;  // wave-uniform
            const int j = j0 + 2 * jj;
            const int rowbase = (((b * OD + zd) * OH + zh) * OW) << 6;
            const int koff = (i << 4) + (j << 2);
            if (qhi) {
                const f4* s = p + rowbase + (q << 6) + koff;        // l=0,1
                ae += s[0];
                ao += s[1];
            }
            if (qlo) {
                const f4* s = p + rowbase + ((q - 1) << 6) + koff + 2; // l=2,3
                ae += s[0];
                ao += s[1];
            }
        }
    }

    ae *= inv;
    ao *= inv;

    // out f4 index: ((b*64 + d)*128 + h)*128 + 2q
    const int n = ((((b << 6) + d) << 7) + h) * 128 + (q << 1);
    __builtin_nontemporal_store(ae, &out[n]);
    __builtin_nontemporal_store(ao, &out[n + 1]);
}

extern "C" void kernel_launch(void* const* d_in, const int* in_sizes, int n_in,
                              void* d_out, int out_size, void* d_ws, size_t ws_size,
                              hipStream_t stream)
{
    const f4* patches = (const f4*)d_in[0];   // [2,31,63,63,256] f32
    f4* out = (f4*)d_out;                     // [2,64,128,128,4] f32

    const int blocks = 2 * 16 * 32;           // b * d-quads * h-quads = 1024
    fold_quad_kernel<<<blocks, 1024, 0, stream>>>(patches, out);
}

// Round 6
// 52.761 us; speedup vs baseline: 2.6538x; 1.0159x over previous
//
#include <hip/hip_runtime.h>

// CombinePatches: col2im/fold of 4x4x4 stride-2 volume patches + divide by
// overlap count. Gather formulation: each output voxel (b,d,h,w,c) sums the
// <=8 patch elements that scatter onto it (kernel offset i must satisfy
// i ≡ d (mod 2), 0 <= (d-i)/2 < od; same for h,w). Count = #valid combos,
// always in {1,2,4,8} -> exact fp32 reciprocal.
//
// FINAL (round 6 = round 1 restored): measured ladder —
//   r1 this kernel          52.55 us  (best)
//   r2 pair+NT-store        53.27 us  (request-rate not the limiter)
//   r3 NT loads            140.0  us  (cache merging is essential)
//   r4 ILP4                 64.6  us  (TLP > ILP here)
//   r5 dense 4x4 quad       53.60 us  (DRAM locality not the limiter)
// Effective 5.4 TB/s = 86% of float4-copy ceiling; traffic is bijective-
// minimal (252 MB read + 33.5 MB write). Limiter: HBM/L3 service rate for
// 16-32B/lane gather at 1KB stride, fixed by the problem's patch layout.

constexpr int Bsz = 2;
constexpr int Dd  = 64;
constexpr int Hh  = 128;
constexpr int Ww  = 128;
constexpr int OD = 31;
constexpr int OH = 63;
constexpr int OW = 63;
// patch inner layout: [kd,kh,kw,C] -> float4 offset = i*16 + j*4 + l, 64 float4/patch

__global__ __launch_bounds__(256) void fold_gather_kernel(
    const float4* __restrict__ p, float4* __restrict__ out)
{
    int n = blockIdx.x * 256 + threadIdx.x;      // one thread per (b,d,h,w)
    int w = n & (Ww - 1);
    int h = (n >> 7) & (Hh - 1);
    int d = (n >> 14) & (Dd - 1);
    int b = n >> 20;

    int i0 = d & 1, j0 = h & 1, l0 = w & 1;

    float4 acc = make_float4(0.f, 0.f, 0.f, 0.f);
    int cnt = 0;

    #pragma unroll
    for (int ii = 0; ii < 2; ++ii) {
        int i  = i0 + 2 * ii;
        int zd = (d - i) >> 1;                   // d-i even by construction
        if ((unsigned)zd >= (unsigned)OD) continue;
        #pragma unroll
        for (int jj = 0; jj < 2; ++jj) {
            int j  = j0 + 2 * jj;
            int zh = (h - j) >> 1;
            if ((unsigned)zh >= (unsigned)OH) continue;
            #pragma unroll
            for (int ll = 0; ll < 2; ++ll) {
                int l  = l0 + 2 * ll;
                int zw = (w - l) >> 1;
                if ((unsigned)zw >= (unsigned)OW) continue;
                int pidx = ((((b * OD + zd) * OH + zh) * OW + zw) << 6)
                           + (i << 4) + (j << 2) + l;   // fits int (~15.7M)
                float4 v = p[pidx];
                acc.x += v.x; acc.y += v.y; acc.z += v.z; acc.w += v.w;
                ++cnt;
            }
        }
    }

    float inv = 1.0f / (float)cnt;               // cnt in {1,2,4,8}: exact
    acc.x *= inv; acc.y *= inv; acc.z *= inv; acc.w *= inv;
    out[n] = acc;
}

extern "C" void kernel_launch(void* const* d_in, const int* in_sizes, int n_in,
                              void* d_out, int out_size, void* d_ws, size_t ws_size,
                              hipStream_t stream)
{
    const float4* patches = (const float4*)d_in[0];   // [2,31,63,63,256] f32
    // d_in[1] ("inputs") is only used for its shape in the reference.
    float4* out = (float4*)d_out;                     // [2,64,128,128,4] f32

    const int total = Bsz * Dd * Hh * Ww;             // 2^21 threads
    fold_gather_kernel<<<total / 256, 256, 0, stream>>>(patches, out);
}